// Round 1
// baseline (486.891 us; speedup 1.0000x reference)
//
#include <hip/hip_runtime.h>

#define S_DIM 128
#define I_DIM 384
#define IN_DIM 256
#define PD 32
#define ODIM 128

typedef __attribute__((ext_vector_type(8))) __bf16 bf16x8;
typedef __attribute__((ext_vector_type(4))) float f32x4;

#define MFMA16(a, b, c) __builtin_amdgcn_mfma_f32_16x16x32_bf16((a), (b), (c), 0, 0, 0)

__device__ inline unsigned short f2bf(float f) {
    unsigned int u = __builtin_bit_cast(unsigned int, f);
    unsigned int r = (u + 0x7FFFu + ((u >> 16) & 1u)) >> 16;
    return (unsigned short)r;
}

// ---------------- prep: cast/transpose weights to bf16 ----------------
// WpT[f][k] = Wp[k][f]            (64 x 256)
// W2t[f][e*32+d] = W2[d][e][f]    (128 x 1024)
__global__ void prep_cast(const float* __restrict__ Wp, const float* __restrict__ W2,
                          unsigned short* __restrict__ WpT, unsigned short* __restrict__ W2t) {
    int t = blockIdx.x * 256 + threadIdx.x;
    if (t < 64 * 256) {
        int f = t >> 8, k = t & 255;
        WpT[t] = f2bf(Wp[k * 64 + f]);
    }
    if (t < 128 * 1024) {
        int f = t >> 10, de = t & 1023;
        int e = de >> 5, d = de & 31;
        W2t[t] = f2bf(W2[(d * 32 + e) * 128 + f]);
    }
}

// ---------------- norm: gram of mask ----------------
__global__ void norm_kernel(const float* __restrict__ mask, float* __restrict__ normv) {
    __shared__ float mi[S_DIM][16];
    __shared__ float mj[S_DIM][16];
    int t = threadIdx.x;
    int i0 = blockIdx.y * 16, j0 = blockIdx.x * 16;
    for (int p = 0; p < 8; ++p) {
        int s = p * 16 + (t >> 4);
        int c = t & 15;
        mi[s][c] = mask[s * I_DIM + i0 + c];
        mj[s][c] = mask[s * I_DIM + j0 + c];
    }
    __syncthreads();
    int ii = t >> 4, jj = t & 15;
    float acc = 0.f;
#pragma unroll 8
    for (int s = 0; s < S_DIM; ++s) acc += mi[s][ii] * mj[s][jj];
    normv[(i0 + ii) * I_DIM + (j0 + jj)] = acc;
}

// ---------------- LN + projection (bf16 MFMA) ----------------
// block = 256 thr (4 waves), 64 rows/block, grid = 49152/64 = 768
// outputs: lT[(i*32+d)][s], rT[(i*32+e)][s]  bf16 (12288 x 128 each)
__global__ __launch_bounds__(256, 2) void ln_proj(const float* __restrict__ x,
                                                  const float* __restrict__ mask,
                                                  const float* __restrict__ bias,
                                                  const unsigned short* __restrict__ WpT_g,
                                                  unsigned short* __restrict__ lT,
                                                  unsigned short* __restrict__ rT) {
    __shared__ unsigned short xsh[64 * 264];   // [row][k], pitch 264
    __shared__ unsigned short wpT[64 * 264];   // [f][k], pitch 264
    int t = threadIdx.x;
    int w = t >> 6, lane = t & 63;
    int R0 = blockIdx.x * 64;

    // stage WpT into LDS
    {
        int f = t >> 2, kq = (t & 3) * 64;
#pragma unroll
        for (int i = 0; i < 8; ++i) {
            int k = kq + i * 8;
            *(uint4*)&wpT[f * 264 + k] = *(const uint4*)&WpT_g[f * 256 + k];
        }
    }

    // LayerNorm: wave w handles rows [w*16, w*16+16)
    for (int it = 0; it < 16; ++it) {
        int row = w * 16 + it;
        const float4 v = *(const float4*)(x + (size_t)(R0 + row) * IN_DIM + lane * 4);
        float s1 = v.x + v.y + v.z + v.w;
        float s2 = v.x * v.x + v.y * v.y + v.z * v.z + v.w * v.w;
#pragma unroll
        for (int off = 32; off >= 1; off >>= 1) {
            s1 += __shfl_xor(s1, off);
            s2 += __shfl_xor(s2, off);
        }
        float mu = s1 * (1.f / 256.f);
        float var = s2 * (1.f / 256.f) - mu * mu;
        float rs = rsqrtf(var + 1e-5f);
        unsigned int h0 = f2bf((v.x - mu) * rs);
        unsigned int h1 = f2bf((v.y - mu) * rs);
        unsigned int h2 = f2bf((v.z - mu) * rs);
        unsigned int h3 = f2bf((v.w - mu) * rs);
        uint2 pk;
        pk.x = h0 | (h1 << 16);
        pk.y = h2 | (h3 << 16);
        *(uint2*)&xsh[row * 264 + lane * 4] = pk;
    }
    __syncthreads();

    // MFMA projection: act[row][f] = sum_k xn[row][k] * Wp[k][f]
    int l15 = lane & 15, q = lane >> 4;
    f32x4 acc[4];
#pragma unroll
    for (int nt = 0; nt < 4; ++nt) acc[nt] = (f32x4){0.f, 0.f, 0.f, 0.f};

    for (int k0 = 0; k0 < 256; k0 += 32) {
        bf16x8 a = *(bf16x8*)&xsh[(w * 16 + l15) * 264 + k0 + q * 8];
#pragma unroll
        for (int nt = 0; nt < 4; ++nt) {
            bf16x8 b = *(bf16x8*)&wpT[(nt * 16 + l15) * 264 + k0 + q * 8];
            acc[nt] = MFMA16(a, b, acc[nt]);
        }
    }

    // epilogue: +bias, *mask, scatter-store bf16 transposed
    int s = R0 / I_DIM;   // whole block shares one s (384 % 64 == 0)
    float mval[4];
    int iv[4];
#pragma unroll
    for (int reg = 0; reg < 4; ++reg) {
        int Rr = R0 + w * 16 + q * 4 + reg;
        iv[reg] = Rr - s * I_DIM;
        mval[reg] = mask[Rr];  // mask flat index == row index
    }
#pragma unroll
    for (int nt = 0; nt < 4; ++nt) {
        int f = nt * 16 + l15;
        float bv = bias[f];
        unsigned short* dst = (f < 32) ? lT : rT;
        int fc = f & 31;
#pragma unroll
        for (int reg = 0; reg < 4; ++reg) {
            float val = (acc[nt][reg] + bv) * mval[reg];
            dst[(size_t)(iv[reg] * 32 + fc) * 128 + s] = f2bf(val);
        }
    }
}

// ---------------- fused outer + contraction ----------------
// grid (96, 96): bx = j-block (4 j), by = i-block (4 i). 256 thr (4 waves).
__global__ __launch_bounds__(256, 2) void fused_kernel(const unsigned short* __restrict__ lT,
                                                       const unsigned short* __restrict__ rT,
                                                       const unsigned short* __restrict__ W2t,
                                                       const float* __restrict__ normv,
                                                       const float* __restrict__ out_bias,
                                                       float* __restrict__ out) {
    __shared__ unsigned short lsh[128 * 136];   // stage1: l[m][k]; stage2: G^T[col][row]
    __shared__ unsigned short rsh[128 * 136];   // r[n][k]
    __shared__ float inv_norm[16];
    __shared__ float bias_sh[128];

    int t = threadIdx.x;
    int bx = blockIdx.x, by = blockIdx.y;
    int colL0 = by * 128, colR0 = bx * 128;

    // stage l/r tiles: [m][k], conflict-free b128 in/out
    {
        int m = t >> 1, kh = (t & 1) * 64;
#pragma unroll
        for (int i = 0; i < 8; ++i) {
            int k = kh + i * 8;
            *(uint4*)&lsh[m * 136 + k] = *(const uint4*)&lT[(size_t)(colL0 + m) * 128 + k];
            *(uint4*)&rsh[m * 136 + k] = *(const uint4*)&rT[(size_t)(colR0 + m) * 128 + k];
        }
    }
    if (t < 16) {
        int ii = t >> 2, jj = t & 3;
        inv_norm[t] = 1.0f / (normv[(by * 4 + ii) * I_DIM + bx * 4 + jj] + 0.001f);
    }
    if (t < 128) bias_sh[t] = out_bias[t];
    __syncthreads();

    int w = t >> 6, lane = t & 63, l15 = lane & 15, q = lane >> 4;

    // ---- stage 1: G[m][n] = sum_s l[m][s] r[n][s], wave w does rows [w*32, w*32+32)
    f32x4 acc[2][8];
#pragma unroll
    for (int mt = 0; mt < 2; ++mt)
#pragma unroll
        for (int nt = 0; nt < 8; ++nt) acc[mt][nt] = (f32x4){0.f, 0.f, 0.f, 0.f};

    for (int k0 = 0; k0 < 128; k0 += 32) {
        bf16x8 a0 = *(bf16x8*)&lsh[(w * 32 + l15) * 136 + k0 + q * 8];
        bf16x8 a1 = *(bf16x8*)&lsh[(w * 32 + 16 + l15) * 136 + k0 + q * 8];
#pragma unroll
        for (int nt = 0; nt < 8; ++nt) {
            bf16x8 b = *(bf16x8*)&rsh[(nt * 16 + l15) * 136 + k0 + q * 8];
            acc[0][nt] = MFMA16(a0, b, acc[0][nt]);
            acc[1][nt] = MFMA16(a1, b, acc[1][nt]);
        }
    }
    __syncthreads();   // everyone done reading lsh before overwrite

    // ---- write G transposed (G^T[col][row]) as bf16 into lsh region, b64 packed
#pragma unroll
    for (int mt = 0; mt < 2; ++mt) {
        int rowb = w * 32 + mt * 16 + q * 4;
#pragma unroll
        for (int nt = 0; nt < 8; ++nt) {
            int col = nt * 16 + l15;
            unsigned int lo = (unsigned int)f2bf(acc[mt][nt][0]) | ((unsigned int)f2bf(acc[mt][nt][1]) << 16);
            unsigned int hi = (unsigned int)f2bf(acc[mt][nt][2]) | ((unsigned int)f2bf(acc[mt][nt][3]) << 16);
            uint2 pk; pk.x = lo; pk.y = hi;
            *(uint2*)&lsh[col * 136 + rowb] = pk;
        }
    }
    __syncthreads();

    // ---- stage 2: out[p][f] = sum_{kflat} G[ii*32+d][jj*32+e] * W[d][e][f]
    //      kflat = e*32 + d; A-frag: p = lane&15 -> (ii=p>>2, jj=p&3), d = q*8+j, e = k0
    f32x4 c2[2];
    c2[0] = (f32x4){0.f, 0.f, 0.f, 0.f};
    c2[1] = (f32x4){0.f, 0.f, 0.f, 0.f};
    int ii_a = l15 >> 2, jj_a = l15 & 3;
#pragma unroll 4
    for (int k0 = 0; k0 < 32; ++k0) {
        bf16x8 a = *(bf16x8*)&lsh[(jj_a * 32 + k0) * 136 + ii_a * 32 + q * 8];
#pragma unroll
        for (int u = 0; u < 2; ++u) {
            int f = (2 * w + u) * 16 + l15;
            bf16x8 b = *(const bf16x8*)&W2t[(size_t)f * 1024 + k0 * 32 + q * 8];
            c2[u] = MFMA16(a, b, c2[u]);
        }
    }

    // ---- epilogue: rows of D are pairs p = q*4+reg, cols are f
#pragma unroll
    for (int u = 0; u < 2; ++u) {
        int f = (2 * w + u) * 16 + l15;
        float bv = bias_sh[f];
#pragma unroll
        for (int reg = 0; reg < 4; ++reg) {
            int p = q * 4 + reg;
            int ii = p >> 2, jj = p & 3;
            float val = (c2[u][reg] + bv) * inv_norm[p];
            out[(size_t)((by * 4 + ii) * I_DIM + bx * 4 + jj) * 128 + f] = val;
        }
    }
}

extern "C" void kernel_launch(void* const* d_in, const int* in_sizes, int n_in,
                              void* d_out, int out_size, void* d_ws, size_t ws_size,
                              hipStream_t stream) {
    const float* node = (const float*)d_in[0];
    const float* mask = (const float*)d_in[1];
    const float* Wp   = (const float*)d_in[2];
    const float* bp   = (const float*)d_in[3];
    const float* W2   = (const float*)d_in[4];
    const float* bo   = (const float*)d_in[5];
    float* out = (float*)d_out;

    char* ws = (char*)d_ws;
    unsigned short* lT   = (unsigned short*)(ws);             // 12288*128*2 = 3,145,728
    unsigned short* rT   = (unsigned short*)(ws + 3145728);   // 3,145,728
    unsigned short* W2t  = (unsigned short*)(ws + 6291456);   // 128*1024*2 = 262,144
    unsigned short* WpT  = (unsigned short*)(ws + 6553600);   // 64*256*2 = 32,768
    float*          nrm  = (float*)(ws + 6586368);            // 384*384*4 = 589,824

    hipLaunchKernelGGL(prep_cast, dim3(512), dim3(256), 0, stream, Wp, W2, WpT, W2t);
    hipLaunchKernelGGL(norm_kernel, dim3(24, 24), dim3(256), 0, stream, mask, nrm);
    hipLaunchKernelGGL(ln_proj, dim3(768), dim3(256), 0, stream, node, mask, bp, WpT, lT, rT);
    hipLaunchKernelGGL(fused_kernel, dim3(96, 96), dim3(256), 0, stream, lT, rT, W2t, nrm, bo, out);
}

// Round 2
// 423.250 us; speedup vs baseline: 1.1504x; 1.1504x over previous
//
#include <hip/hip_runtime.h>

#define S_DIM 128
#define I_DIM 384
#define IN_DIM 256
#define PD 32
#define ODIM 128

typedef __attribute__((ext_vector_type(8))) __bf16 bf16x8;
typedef __attribute__((ext_vector_type(4))) float f32x4;

#define MFMA16(a, b, c) __builtin_amdgcn_mfma_f32_16x16x32_bf16((a), (b), (c), 0, 0, 0)

__device__ inline unsigned short f2bf(float f) {
    unsigned int u = __builtin_bit_cast(unsigned int, f);
    unsigned int r = (u + 0x7FFFu + ((u >> 16) & 1u)) >> 16;
    return (unsigned short)r;
}

// ---------------- prep: cast/transpose weights to bf16 ----------------
__global__ void prep_cast(const float* __restrict__ Wp, const float* __restrict__ W2,
                          unsigned short* __restrict__ WpT, unsigned short* __restrict__ W2t) {
    int t = blockIdx.x * 256 + threadIdx.x;
    if (t < 64 * 256) {
        int f = t >> 8, k = t & 255;
        WpT[t] = f2bf(Wp[k * 64 + f]);
    }
    if (t < 128 * 1024) {
        int f = t >> 10, de = t & 1023;
        int e = de >> 5, d = de & 31;
        W2t[t] = f2bf(W2[(d * 32 + e) * 128 + f]);
    }
}

// ---------------- norm: gram of mask ----------------
__global__ void norm_kernel(const float* __restrict__ mask, float* __restrict__ normv) {
    __shared__ float mi[S_DIM][16];
    __shared__ float mj[S_DIM][16];
    int t = threadIdx.x;
    int i0 = blockIdx.y * 16, j0 = blockIdx.x * 16;
    for (int p = 0; p < 8; ++p) {
        int s = p * 16 + (t >> 4);
        int c = t & 15;
        mi[s][c] = mask[s * I_DIM + i0 + c];
        mj[s][c] = mask[s * I_DIM + j0 + c];
    }
    __syncthreads();
    int ii = t >> 4, jj = t & 15;
    float acc = 0.f;
#pragma unroll 8
    for (int s = 0; s < S_DIM; ++s) acc += mi[s][ii] * mj[s][jj];
    normv[(i0 + ii) * I_DIM + (j0 + jj)] = acc;
}

// ---------------- LN + projection (bf16 MFMA), i-major for coalesced T-store ----
// grid = 768: block b -> i = b>>1, s0 = (b&1)*64. 64 s-rows per block.
__global__ __launch_bounds__(256, 2) void ln_proj(const float* __restrict__ x,
                                                  const float* __restrict__ mask,
                                                  const float* __restrict__ bias,
                                                  const unsigned short* __restrict__ WpT_g,
                                                  unsigned short* __restrict__ lT,
                                                  unsigned short* __restrict__ rT) {
    __shared__ unsigned short xsh[64 * 264];   // [s-row][k], pitch 264
    __shared__ unsigned short wpT[64 * 264];   // [f][k], pitch 264
    int t = threadIdx.x;
    int w = t >> 6, lane = t & 63;
    int i = blockIdx.x >> 1;
    int s0 = (blockIdx.x & 1) * 64;

    // stage WpT into LDS
    {
        int f = t >> 2, kq = (t & 3) * 64;
#pragma unroll
        for (int p = 0; p < 8; ++p) {
            int k = kq + p * 8;
            *(uint4*)&wpT[f * 264 + k] = *(const uint4*)&WpT_g[f * 256 + k];
        }
    }

    // LayerNorm rows (s0 + w*16 + it) of column i; pipelined loads depth 4
    float4 vbuf[4];
#pragma unroll
    for (int p = 0; p < 4; ++p)
        vbuf[p] = *(const float4*)(x + ((size_t)(s0 + w * 16 + p) * I_DIM + i) * IN_DIM + lane * 4);

    for (int it = 0; it < 16; ++it) {
        float4 v = vbuf[it & 3];
        if (it + 4 < 16)
            vbuf[it & 3] = *(const float4*)(x + ((size_t)(s0 + w * 16 + it + 4) * I_DIM + i) * IN_DIM + lane * 4);
        float s1 = v.x + v.y + v.z + v.w;
        float s2 = v.x * v.x + v.y * v.y + v.z * v.z + v.w * v.w;
#pragma unroll
        for (int off = 32; off >= 1; off >>= 1) {
            s1 += __shfl_xor(s1, off);
            s2 += __shfl_xor(s2, off);
        }
        float mu = s1 * (1.f / 256.f);
        float var = s2 * (1.f / 256.f) - mu * mu;
        float rs = rsqrtf(var + 1e-5f);
        unsigned int h0 = f2bf((v.x - mu) * rs);
        unsigned int h1 = f2bf((v.y - mu) * rs);
        unsigned int h2 = f2bf((v.z - mu) * rs);
        unsigned int h3 = f2bf((v.w - mu) * rs);
        uint2 pk;
        pk.x = h0 | (h1 << 16);
        pk.y = h2 | (h3 << 16);
        *(uint2*)&xsh[(w * 16 + it) * 264 + lane * 4] = pk;
    }
    __syncthreads();

    // MFMA projection: act[srow][f] = sum_k xn[srow][k] * Wp[k][f]
    int l15 = lane & 15, q = lane >> 4;
    f32x4 acc[4];
#pragma unroll
    for (int nt = 0; nt < 4; ++nt) acc[nt] = (f32x4){0.f, 0.f, 0.f, 0.f};

    for (int k0 = 0; k0 < 256; k0 += 32) {
        bf16x8 a = *(bf16x8*)&xsh[(w * 16 + l15) * 264 + k0 + q * 8];
#pragma unroll
        for (int nt = 0; nt < 4; ++nt) {
            bf16x8 b = *(bf16x8*)&wpT[(nt * 16 + l15) * 264 + k0 + q * 8];
            acc[nt] = MFMA16(a, b, acc[nt]);
        }
    }

    // mask per s-row
    float mval[4];
#pragma unroll
    for (int reg = 0; reg < 4; ++reg)
        mval[reg] = mask[(size_t)(s0 + w * 16 + q * 4 + reg) * I_DIM + i];

    __syncthreads();   // all xsh reads done; reuse as transpose buffer
    unsigned short* trsh = xsh;   // [f][s-local], pitch 72

#pragma unroll
    for (int nt = 0; nt < 4; ++nt) {
        int f = nt * 16 + l15;
        float bv = bias[f];
        unsigned int lo = (unsigned int)f2bf((acc[nt][0] + bv) * mval[0]) |
                          ((unsigned int)f2bf((acc[nt][1] + bv) * mval[1]) << 16);
        unsigned int hi = (unsigned int)f2bf((acc[nt][2] + bv) * mval[2]) |
                          ((unsigned int)f2bf((acc[nt][3] + bv) * mval[3]) << 16);
        uint2 pk; pk.x = lo; pk.y = hi;
        *(uint2*)&trsh[f * 72 + w * 16 + q * 4] = pk;
    }
    __syncthreads();

    // coalesced store: thread t -> f-row fr = t>>2, s-offset (t&3)*16
    {
        int fr = t >> 2, so = (t & 3) * 16;
        unsigned short* dst = ((fr < 32) ? lT : rT) + ((size_t)(i * 32 + (fr & 31)) * 128 + s0 + so);
        *(uint4*)dst = *(uint4*)&trsh[fr * 72 + so];
        *(uint4*)(dst + 8) = *(uint4*)&trsh[fr * 72 + so + 8];
    }
}

// ---------------- fused outer + contraction ----------------
// grid (96, 96). 256 thr (4 waves). LDS: one 128x136 bf16 buffer (r-tile, then G^T).
__global__ __launch_bounds__(256, 4) void fused_kernel(const unsigned short* __restrict__ lT,
                                                       const unsigned short* __restrict__ rT,
                                                       const unsigned short* __restrict__ W2t,
                                                       const float* __restrict__ normv,
                                                       const float* __restrict__ out_bias,
                                                       float* __restrict__ out) {
    __shared__ unsigned short sh[128 * 136];
    __shared__ float inv_norm[16];
    __shared__ float bias_sh[128];

    int t = threadIdx.x;
    int bx = blockIdx.x, by = blockIdx.y;
    int colL0 = by * 128, colR0 = bx * 128;
    int w = t >> 6, lane = t & 63, l15 = lane & 15, q = lane >> 4;

    // ---- prefetch stage-1 A fragments (k0 = 0) straight from global lT
    const unsigned short* lbase = lT + (size_t)(colL0 + w * 32 + l15) * 128 + q * 8;
    bf16x8 a0 = *(const bf16x8*)(lbase);
    bf16x8 a1 = *(const bf16x8*)(lbase + 16 * 128);

    // ---- stage r-tile into LDS: row m, chunk c -> bank-group (m+c)%8, conflict-free
    {
        int m0 = t >> 3, c0 = (t & 7) * 8;
        const unsigned short* rbase = rT + (size_t)(colR0 + m0) * 128 + c0;
#pragma unroll
        for (int p = 0; p < 4; ++p) {
            *(uint4*)&sh[(m0 + p * 32) * 136 + c0] = *(const uint4*)(rbase + (size_t)p * 32 * 128);
            *(uint4*)&sh[(m0 + p * 32) * 136 + c0 + 64] = *(const uint4*)(rbase + (size_t)p * 32 * 128 + 64);
        }
    }
    if (t < 16) inv_norm[t] = 1.0f / (normv[(by * 4 + (t >> 2)) * I_DIM + bx * 4 + (t & 3)] + 0.001f);
    if (t < 128) bias_sh[t] = out_bias[t];
    __syncthreads();

    // ---- stage 1: G[m][n] = sum_s l[m][s] r[n][s]; wave w rows [w*32, w*32+32)
    f32x4 acc[2][8];
#pragma unroll
    for (int mt = 0; mt < 2; ++mt)
#pragma unroll
        for (int nt = 0; nt < 8; ++nt) acc[mt][nt] = (f32x4){0.f, 0.f, 0.f, 0.f};

#pragma unroll
    for (int k0 = 0; k0 < 4; ++k0) {
        bf16x8 na0 = a0, na1 = a1;
        if (k0 < 3) {
            na0 = *(const bf16x8*)(lbase + (k0 + 1) * 32);
            na1 = *(const bf16x8*)(lbase + 16 * 128 + (k0 + 1) * 32);
        }
#pragma unroll
        for (int nt = 0; nt < 8; ++nt) {
            bf16x8 b = *(bf16x8*)&sh[(nt * 16 + l15) * 136 + k0 * 32 + q * 8];
            acc[0][nt] = MFMA16(a0, b, acc[0][nt]);
            acc[1][nt] = MFMA16(a1, b, acc[1][nt]);
        }
        a0 = na0; a1 = na1;
    }
    __syncthreads();   // all reads of r-tile done

    // ---- overlay: write G^T (bf16) into sh with XOR chunk swizzle
    //      element (n, m) stored at sh[n*136 + ((m>>3) ^ (n>>5))*8 + (m&7)]
#pragma unroll
    for (int mt = 0; mt < 2; ++mt) {
        int rowb = w * 32 + mt * 16 + q * 4;
        int chnk = rowb >> 3;
        int win = rowb & 7;
#pragma unroll
        for (int nt = 0; nt < 8; ++nt) {
            int col = nt * 16 + l15;
            int cs = chnk ^ (col >> 5);
            unsigned int lo = (unsigned int)f2bf(acc[mt][nt][0]) | ((unsigned int)f2bf(acc[mt][nt][1]) << 16);
            unsigned int hi = (unsigned int)f2bf(acc[mt][nt][2]) | ((unsigned int)f2bf(acc[mt][nt][3]) << 16);
            uint2 pk; pk.x = lo; pk.y = hi;
            *(uint2*)&sh[col * 136 + cs * 8 + win] = pk;
        }
    }
    __syncthreads();

    // ---- stage 2: out[p][f] = sum_{e,d} G[ii*32+d][jj*32+e] * W[d][e][f]
    f32x4 c2[2];
    c2[0] = (f32x4){0.f, 0.f, 0.f, 0.f};
    c2[1] = (f32x4){0.f, 0.f, 0.f, 0.f};
    int ii_a = l15 >> 2, jj_a = l15 & 3;
    // A(k0) = sh[(jj_a*32+k0)*136 + ((ii_a*4+q) ^ jj_a)*8], swizzle-consistent
    int acs = jj_a * 32 * 136 + (((ii_a * 4 + q) ^ jj_a) * 8);
    const unsigned short* wb0 = W2t + (size_t)((2 * w + 0) * 16 + l15) * 1024 + q * 8;
    const unsigned short* wb1 = W2t + (size_t)((2 * w + 1) * 16 + l15) * 1024 + q * 8;

    bf16x8 a_c = *(bf16x8*)&sh[acs];
    bf16x8 b_c0 = *(const bf16x8*)(wb0);
    bf16x8 b_c1 = *(const bf16x8*)(wb1);
    bf16x8 a_n = *(bf16x8*)&sh[acs + 136];
    bf16x8 b_n0 = *(const bf16x8*)(wb0 + 32);
    bf16x8 b_n1 = *(const bf16x8*)(wb1 + 32);

#pragma unroll
    for (int k0 = 0; k0 < 32; k0 += 2) {
        bf16x8 a_p = a_c, b_p0 = b_c0, b_p1 = b_c1;
        bf16x8 a_r = a_n, b_r0 = b_n0, b_r1 = b_n1;
        if (k0 + 2 < 32) {
            a_p = *(bf16x8*)&sh[acs + (k0 + 2) * 136];
            b_p0 = *(const bf16x8*)(wb0 + (k0 + 2) * 32);
            b_p1 = *(const bf16x8*)(wb1 + (k0 + 2) * 32);
            a_r = *(bf16x8*)&sh[acs + (k0 + 3) * 136];
            b_r0 = *(const bf16x8*)(wb0 + (k0 + 3) * 32);
            b_r1 = *(const bf16x8*)(wb1 + (k0 + 3) * 32);
        }
        c2[0] = MFMA16(a_c, b_c0, c2[0]);
        c2[1] = MFMA16(a_c, b_c1, c2[1]);
        c2[0] = MFMA16(a_n, b_n0, c2[0]);
        c2[1] = MFMA16(a_n, b_n1, c2[1]);
        a_c = a_p; b_c0 = b_p0; b_c1 = b_p1;
        a_n = a_r; b_n0 = b_r0; b_n1 = b_r1;
    }

    // ---- epilogue: D rows = pairs p = q*4+reg, cols = f
#pragma unroll
    for (int u = 0; u < 2; ++u) {
        int f = (2 * w + u) * 16 + l15;
        float bv = bias_sh[f];
#pragma unroll
        for (int reg = 0; reg < 4; ++reg) {
            int p = q * 4 + reg;
            int ii = p >> 2, jj = p & 3;
            float val = (c2[u][reg] + bv) * inv_norm[p];
            out[(size_t)((by * 4 + ii) * I_DIM + bx * 4 + jj) * 128 + f] = val;
        }
    }
}

extern "C" void kernel_launch(void* const* d_in, const int* in_sizes, int n_in,
                              void* d_out, int out_size, void* d_ws, size_t ws_size,
                              hipStream_t stream) {
    const float* node = (const float*)d_in[0];
    const float* mask = (const float*)d_in[1];
    const float* Wp   = (const float*)d_in[2];
    const float* bp   = (const float*)d_in[3];
    const float* W2   = (const float*)d_in[4];
    const float* bo   = (const float*)d_in[5];
    float* out = (float*)d_out;

    char* ws = (char*)d_ws;
    unsigned short* lT  = (unsigned short*)(ws);             // 12288*128*2 = 3,145,728
    unsigned short* rT  = (unsigned short*)(ws + 3145728);   // 3,145,728
    unsigned short* W2t = (unsigned short*)(ws + 6291456);   // 262,144
    unsigned short* WpT = (unsigned short*)(ws + 6553600);   // 32,768
    float*          nrm = (float*)(ws + 6586368);            // 589,824

    hipLaunchKernelGGL(prep_cast, dim3(512), dim3(256), 0, stream, Wp, W2, WpT, W2t);
    hipLaunchKernelGGL(norm_kernel, dim3(24, 24), dim3(256), 0, stream, mask, nrm);
    hipLaunchKernelGGL(ln_proj, dim3(768), dim3(256), 0, stream, node, mask, bp, WpT, lT, rT);
    hipLaunchKernelGGL(fused_kernel, dim3(96, 96), dim3(256), 0, stream, lT, rT, W2t, nrm, bo, out);
}

// Round 3
// 332.001 us; speedup vs baseline: 1.4665x; 1.2748x over previous
//
#include <hip/hip_runtime.h>

#define S_DIM 128
#define I_DIM 384
#define IN_DIM 256
#define PD 32
#define ODIM 128

typedef __attribute__((ext_vector_type(8))) __bf16 bf16x8;
typedef __attribute__((ext_vector_type(4))) float f32x4;

#define MFMA16(a, b, c) __builtin_amdgcn_mfma_f32_16x16x32_bf16((a), (b), (c), 0, 0, 0)

__device__ inline unsigned short f2bf(float f) {
    unsigned int u = __builtin_bit_cast(unsigned int, f);
    unsigned int r = (u + 0x7FFFu + ((u >> 16) & 1u)) >> 16;
    return (unsigned short)r;
}

// ---------------- prep: cast/transpose weights to bf16 ----------------
__global__ void prep_cast(const float* __restrict__ Wp, const float* __restrict__ W2,
                          unsigned short* __restrict__ WpT, unsigned short* __restrict__ W2t) {
    int t = blockIdx.x * 256 + threadIdx.x;
    if (t < 64 * 256) {
        int f = t >> 8, k = t & 255;
        WpT[t] = f2bf(Wp[k * 64 + f]);
    }
    if (t < 128 * 1024) {
        int f = t >> 10, de = t & 1023;
        int e = de >> 5, d = de & 31;
        W2t[t] = f2bf(W2[(d * 32 + e) * 128 + f]);
    }
}

// ---------------- norm: gram of mask -> store INVERSE ----------------
__global__ void norm_kernel(const float* __restrict__ mask, float* __restrict__ invn) {
    __shared__ float mi[S_DIM][16];
    __shared__ float mj[S_DIM][16];
    int t = threadIdx.x;
    int i0 = blockIdx.y * 16, j0 = blockIdx.x * 16;
    for (int p = 0; p < 8; ++p) {
        int s = p * 16 + (t >> 4);
        int c = t & 15;
        mi[s][c] = mask[s * I_DIM + i0 + c];
        mj[s][c] = mask[s * I_DIM + j0 + c];
    }
    __syncthreads();
    int ii = t >> 4, jj = t & 15;
    float acc = 0.f;
#pragma unroll 8
    for (int s = 0; s < S_DIM; ++s) acc += mi[s][ii] * mj[s][jj];
    invn[(i0 + ii) * I_DIM + (j0 + jj)] = 1.0f / (acc + 0.001f);
}

// ---------------- LN + projection (bf16 MFMA), i-major for coalesced T-store ----
__global__ __launch_bounds__(256, 2) void ln_proj(const float* __restrict__ x,
                                                  const float* __restrict__ mask,
                                                  const float* __restrict__ bias,
                                                  const unsigned short* __restrict__ WpT_g,
                                                  unsigned short* __restrict__ lT,
                                                  unsigned short* __restrict__ rT) {
    __shared__ unsigned short xsh[64 * 264];
    __shared__ unsigned short wpT[64 * 264];
    int t = threadIdx.x;
    int w = t >> 6, lane = t & 63;
    int i = blockIdx.x >> 1;
    int s0 = (blockIdx.x & 1) * 64;

    {
        int f = t >> 2, kq = (t & 3) * 64;
#pragma unroll
        for (int p = 0; p < 8; ++p) {
            int k = kq + p * 8;
            *(uint4*)&wpT[f * 264 + k] = *(const uint4*)&WpT_g[f * 256 + k];
        }
    }

    float4 vbuf[4];
#pragma unroll
    for (int p = 0; p < 4; ++p)
        vbuf[p] = *(const float4*)(x + ((size_t)(s0 + w * 16 + p) * I_DIM + i) * IN_DIM + lane * 4);

    for (int it = 0; it < 16; ++it) {
        float4 v = vbuf[it & 3];
        if (it + 4 < 16)
            vbuf[it & 3] = *(const float4*)(x + ((size_t)(s0 + w * 16 + it + 4) * I_DIM + i) * IN_DIM + lane * 4);
        float s1 = v.x + v.y + v.z + v.w;
        float s2 = v.x * v.x + v.y * v.y + v.z * v.z + v.w * v.w;
#pragma unroll
        for (int off = 32; off >= 1; off >>= 1) {
            s1 += __shfl_xor(s1, off);
            s2 += __shfl_xor(s2, off);
        }
        float mu = s1 * (1.f / 256.f);
        float var = s2 * (1.f / 256.f) - mu * mu;
        float rs = rsqrtf(var + 1e-5f);
        unsigned int h0 = f2bf((v.x - mu) * rs);
        unsigned int h1 = f2bf((v.y - mu) * rs);
        unsigned int h2 = f2bf((v.z - mu) * rs);
        unsigned int h3 = f2bf((v.w - mu) * rs);
        uint2 pk;
        pk.x = h0 | (h1 << 16);
        pk.y = h2 | (h3 << 16);
        *(uint2*)&xsh[(w * 16 + it) * 264 + lane * 4] = pk;
    }
    __syncthreads();

    int l15 = lane & 15, q = lane >> 4;
    f32x4 acc[4];
#pragma unroll
    for (int nt = 0; nt < 4; ++nt) acc[nt] = (f32x4){0.f, 0.f, 0.f, 0.f};

    for (int k0 = 0; k0 < 256; k0 += 32) {
        bf16x8 a = *(bf16x8*)&xsh[(w * 16 + l15) * 264 + k0 + q * 8];
#pragma unroll
        for (int nt = 0; nt < 4; ++nt) {
            bf16x8 b = *(bf16x8*)&wpT[(nt * 16 + l15) * 264 + k0 + q * 8];
            acc[nt] = MFMA16(a, b, acc[nt]);
        }
    }

    float mval[4];
#pragma unroll
    for (int reg = 0; reg < 4; ++reg)
        mval[reg] = mask[(size_t)(s0 + w * 16 + q * 4 + reg) * I_DIM + i];

    __syncthreads();
    unsigned short* trsh = xsh;

#pragma unroll
    for (int nt = 0; nt < 4; ++nt) {
        int f = nt * 16 + l15;
        float bv = bias[f];
        unsigned int lo = (unsigned int)f2bf((acc[nt][0] + bv) * mval[0]) |
                          ((unsigned int)f2bf((acc[nt][1] + bv) * mval[1]) << 16);
        unsigned int hi = (unsigned int)f2bf((acc[nt][2] + bv) * mval[2]) |
                          ((unsigned int)f2bf((acc[nt][3] + bv) * mval[3]) << 16);
        uint2 pk; pk.x = lo; pk.y = hi;
        *(uint2*)&trsh[f * 72 + w * 16 + q * 4] = pk;
    }
    __syncthreads();

    {
        int fr = t >> 2, so = (t & 3) * 16;
        unsigned short* dst = ((fr < 32) ? lT : rT) + ((size_t)(i * 32 + (fr & 31)) * 128 + s0 + so);
        *(uint4*)dst = *(uint4*)&trsh[fr * 72 + so];
        *(uint4*)(dst + 8) = *(uint4*)&trsh[fr * 72 + so + 8];
    }
}

// ---------------- kernel A: outer GEMM, writes Gp[pair][k] bf16 (slab-local) ----
// grid (96, slab_i/4). pair row = (by*4+i_loc)*384 + bx*4 + j_loc (by slab-local).
__global__ __launch_bounds__(256, 4) void outer_kernel(const unsigned short* __restrict__ lT,
                                                       const unsigned short* __restrict__ rT,
                                                       unsigned short* __restrict__ Gp,
                                                       int ib0) {
    __shared__ unsigned short sh[128 * 136];
    int t = threadIdx.x;
    int bx = blockIdx.x, by = blockIdx.y;
    int colL0 = (ib0 + by) * 128, colR0 = bx * 128;
    int w = t >> 6, lane = t & 63, l15 = lane & 15, q = lane >> 4;

    const unsigned short* lbase = lT + (size_t)(colL0 + w * 32 + l15) * 128 + q * 8;
    bf16x8 a0 = *(const bf16x8*)(lbase);
    bf16x8 a1 = *(const bf16x8*)(lbase + 16 * 128);

    {
        int m0 = t >> 3, c0 = (t & 7) * 8;
        const unsigned short* rbase = rT + (size_t)(colR0 + m0) * 128 + c0;
#pragma unroll
        for (int p = 0; p < 4; ++p) {
            *(uint4*)&sh[(m0 + p * 32) * 136 + c0] = *(const uint4*)(rbase + (size_t)p * 32 * 128);
            *(uint4*)&sh[(m0 + p * 32) * 136 + c0 + 64] = *(const uint4*)(rbase + (size_t)p * 32 * 128 + 64);
        }
    }
    __syncthreads();

    f32x4 acc[2][8];
#pragma unroll
    for (int mt = 0; mt < 2; ++mt)
#pragma unroll
        for (int nt = 0; nt < 8; ++nt) acc[mt][nt] = (f32x4){0.f, 0.f, 0.f, 0.f};

#pragma unroll
    for (int k0 = 0; k0 < 4; ++k0) {
        bf16x8 na0 = a0, na1 = a1;
        if (k0 < 3) {
            na0 = *(const bf16x8*)(lbase + (k0 + 1) * 32);
            na1 = *(const bf16x8*)(lbase + 16 * 128 + (k0 + 1) * 32);
        }
#pragma unroll
        for (int nt = 0; nt < 8; ++nt) {
            bf16x8 b = *(bf16x8*)&sh[(nt * 16 + l15) * 136 + k0 * 32 + q * 8];
            acc[0][nt] = MFMA16(a0, b, acc[0][nt]);
            acc[1][nt] = MFMA16(a1, b, acc[1][nt]);
        }
        a0 = na0; a1 = na1;
    }
    __syncthreads();

    // G^T (bf16) into sh with XOR chunk swizzle: (n,m) at sh[n*136 + ((m>>3)^(n>>5))*8 + (m&7)]
#pragma unroll
    for (int mt = 0; mt < 2; ++mt) {
        int rowb = w * 32 + mt * 16 + q * 4;
        int chnk = rowb >> 3;
        int win = rowb & 7;
#pragma unroll
        for (int nt = 0; nt < 8; ++nt) {
            int col = nt * 16 + l15;
            int cs = chnk ^ (col >> 5);
            unsigned int lo = (unsigned int)f2bf(acc[mt][nt][0]) | ((unsigned int)f2bf(acc[mt][nt][1]) << 16);
            unsigned int hi = (unsigned int)f2bf(acc[mt][nt][2]) | ((unsigned int)f2bf(acc[mt][nt][3]) << 16);
            uint2 pk; pk.x = lo; pk.y = hi;
            *(uint2*)&sh[col * 136 + cs * 8 + win] = pk;
        }
    }
    __syncthreads();

    // coalesced Gp write: Gp[pair][k], k = e*32+d; 1 KB per wave-instruction
#pragma unroll
    for (int p8 = 0; p8 < 8; ++p8) {
        int g = p8 * 256 + t;
        int pair_loc = g >> 7;            // 0..15
        int c16 = g & 127;                // 16B chunk within 2KB row
        int i_loc = pair_loc >> 2, j_loc = pair_loc & 3;
        int e = c16 >> 2;
        int n = j_loc * 32 + e;
        int cs = (i_loc * 4 + (c16 & 3)) ^ j_loc;
        uint4 v = *(uint4*)&sh[n * 136 + cs * 8];
        size_t row = (size_t)(by * 4 + i_loc) * I_DIM + bx * 4 + j_loc;
        *(uint4*)&Gp[row * 1024 + (size_t)c16 * 8] = v;
    }
}

// ---------------- kernel B: out[pair][f] = Gp[pair][:] . W2t[f][:] ----------------
// grid = pairs_slab/64, 256 thr. A staged via dbuf LDS; B fragments direct (L2-hot).
__global__ __launch_bounds__(256, 4) void contract_kernel(const unsigned short* __restrict__ Gp,
                                                          const unsigned short* __restrict__ W2t,
                                                          const float* __restrict__ invn,
                                                          const float* __restrict__ out_bias,
                                                          float* __restrict__ out,
                                                          int pair0) {
    __shared__ unsigned short Ash[2][64 * 40];   // [row][32k], pitch 40
    int t = threadIdx.x;
    int w = t >> 6, lane = t & 63, l15 = lane & 15, q = lane >> 4;
    int p0 = blockIdx.x * 64;   // slab-local pair base

    int sr = t >> 2, sc = (t & 3) * 8;
    const unsigned short* agp = Gp + (size_t)(p0 + sr) * 1024 + sc;
    *(uint4*)&Ash[0][sr * 40 + sc] = *(const uint4*)(agp);

    f32x4 acc[4][2];
#pragma unroll
    for (int mt = 0; mt < 4; ++mt) {
        acc[mt][0] = (f32x4){0.f, 0.f, 0.f, 0.f};
        acc[mt][1] = (f32x4){0.f, 0.f, 0.f, 0.f};
    }
    const unsigned short* wb0 = W2t + (size_t)(w * 32 + l15) * 1024 + q * 8;
    const unsigned short* wb1 = wb0 + 16 * 1024;

    bf16x8 b0c = *(const bf16x8*)(wb0);
    bf16x8 b1c = *(const bf16x8*)(wb1);
    __syncthreads();

    for (int k0 = 0; k0 < 32; ++k0) {
        int cur = k0 & 1;
        uint4 nxtA;
        bf16x8 b0n = b0c, b1n = b1c;
        if (k0 < 31) {
            nxtA = *(const uint4*)(agp + (k0 + 1) * 32);
            b0n = *(const bf16x8*)(wb0 + (k0 + 1) * 32);
            b1n = *(const bf16x8*)(wb1 + (k0 + 1) * 32);
        }
        bf16x8 a[4];
#pragma unroll
        for (int mt = 0; mt < 4; ++mt)
            a[mt] = *(bf16x8*)&Ash[cur][(mt * 16 + l15) * 40 + q * 8];
#pragma unroll
        for (int mt = 0; mt < 4; ++mt) {
            acc[mt][0] = MFMA16(a[mt], b0c, acc[mt][0]);
            acc[mt][1] = MFMA16(a[mt], b1c, acc[mt][1]);
        }
        if (k0 < 31) *(uint4*)&Ash[1 - cur][sr * 40 + sc] = nxtA;
        b0c = b0n; b1c = b1n;
        __syncthreads();
    }

#pragma unroll
    for (int u = 0; u < 2; ++u) {
        int f = w * 32 + u * 16 + l15;
        float bv = out_bias[f];
#pragma unroll
        for (int mt = 0; mt < 4; ++mt) {
#pragma unroll
            for (int reg = 0; reg < 4; ++reg) {
                int pl = pair0 + p0 + mt * 16 + q * 4 + reg;
                out[(size_t)pl * 128 + f] = (acc[mt][u][reg] + bv) * invn[pl];
            }
        }
    }
}

extern "C" void kernel_launch(void* const* d_in, const int* in_sizes, int n_in,
                              void* d_out, int out_size, void* d_ws, size_t ws_size,
                              hipStream_t stream) {
    const float* node = (const float*)d_in[0];
    const float* mask = (const float*)d_in[1];
    const float* Wp   = (const float*)d_in[2];
    const float* bp   = (const float*)d_in[3];
    const float* W2   = (const float*)d_in[4];
    const float* bo   = (const float*)d_in[5];
    float* out = (float*)d_out;

    char* ws = (char*)d_ws;
    unsigned short* lT  = (unsigned short*)(ws);             // 3,145,728
    unsigned short* rT  = (unsigned short*)(ws + 3145728);   // 3,145,728
    unsigned short* W2t = (unsigned short*)(ws + 6291456);   // 262,144
    unsigned short* WpT = (unsigned short*)(ws + 6553600);   // 32,768
    float*          inv = (float*)(ws + 6586368);            // 589,824
    unsigned short* Gp  = (unsigned short*)(ws + 8388608);   // slab buffer

    // pick largest slab (in i-values) fitting ws: 96 -> 75.5 MB
    int slab_i = 96;
    while (slab_i > 12 && 8388608ull + (size_t)slab_i * 384 * 1024 * 2 > ws_size) slab_i >>= 1;
    int nslab = 384 / slab_i;

    hipLaunchKernelGGL(prep_cast, dim3(512), dim3(256), 0, stream, Wp, W2, WpT, W2t);
    hipLaunchKernelGGL(norm_kernel, dim3(24, 24), dim3(256), 0, stream, mask, inv);
    hipLaunchKernelGGL(ln_proj, dim3(768), dim3(256), 0, stream, node, mask, bp, WpT, lT, rT);

    for (int s = 0; s < nslab; ++s) {
        hipLaunchKernelGGL(outer_kernel, dim3(96, slab_i / 4), dim3(256), 0, stream,
                           lT, rT, Gp, s * (slab_i / 4));
        hipLaunchKernelGGL(contract_kernel, dim3(slab_i * 384 / 64), dim3(256), 0, stream,
                           Gp, W2t, inv, bo, out, s * slab_i * I_DIM);
    }
}